// Round 1
// baseline (43115.948 us; speedup 1.0000x reference)
//
#include <hip/hip_runtime.h>

#define BB 256
#define SS 16
#define II 64
#define DD 128
#define TT 65            // I + 1 (BOS prepended)
#define N_ITEMS 100000
#define BOS_ID  100000

// ---------------- ws layout (bytes) ----------------
#define OFF_LEN 0                        // int lengths[B][S]         16384
#define OFF_ML  16384                    // int maxlen[S]             64
#define OFF_ME  32768                    // float mean_emb[B][S][D]   2 MB
#define OFF_HB  (32768 + 2097152)        // float hB[S][B][D]         2 MB
#define OFF_WT  (OFF_HB + 2097152)       // float wT[3][3][128][128]  589824
#define OFF_FT  (OFF_WT + 589824)        // float fT[128][128]        65536
// total ~4.66 MB

// ---------------- out layout (float elements) ----------------
#define OUT_REPS  0
#define OUT_MASK  (BB*SS*TT*DD)          // 34,078,720
#define OUT_UTYPE (OUT_MASK + BB*SS*TT)  // 34,344,960

// ============ kernel 0: weight transposes ============
__global__ __launch_bounds__(256) void prep_kernel(
    const float* __restrict__ w0, const float* __restrict__ w1,
    const float* __restrict__ w2, const float* __restrict__ fus_w,
    float* __restrict__ wT, float* __restrict__ fT)
{
    int idx = blockIdx.x * 256 + threadIdx.x;
    if (idx < 3 * 3 * 128 * 128) {
        int L  = idx / 49152;
        int r  = idx % 49152;
        int k  = r / 16384;
        int ci = (r >> 7) & 127;
        int co = r & 127;
        const float* w = (L == 0) ? w0 : ((L == 1) ? w1 : w2);
        wT[idx] = w[(co * 128 + ci) * 3 + k];   // OIH -> [L][k][ci][co]
    } else if (idx < 3 * 3 * 128 * 128 + 128 * 128) {
        int f  = idx - 3 * 3 * 128 * 128;
        int ci = f >> 7;
        int j  = f & 127;
        fT[f] = fus_w[j * 256 + ci];            // [j][2D] -> [ci][j] (tc half)
    }
}

// ============ kernel 1: lengths, per-s max, u_type ============
__global__ __launch_bounds__(256) void len_kernel(
    const int* __restrict__ item_id, const int* __restrict__ u_type,
    int* __restrict__ lengths, int* __restrict__ maxlen,
    float* __restrict__ u_out)
{
    int s = blockIdx.x;     // 16 blocks
    int b = threadIdx.x;    // 256 threads
    const int* row = item_id + (b * SS + s) * II;
    int cnt = 0;
    for (int i = 0; i < II; ++i) cnt += (row[i] > 0);
    lengths[b * SS + s] = cnt;
    __shared__ int red[256];
    red[b] = cnt;
    __syncthreads();
    for (int off = 128; off > 0; off >>= 1) {
        if (b < off) red[b] = max(red[b], red[b + off]);
        __syncthreads();
    }
    if (b == 0) maxlen[s] = red[0];
    if (s == 0) u_out[b] = (float)u_type[b];
}

// ============ kernel 2: masks + mean_emb ============
__global__ __launch_bounds__(128) void mean_kernel(
    const int* __restrict__ item_id, const int* __restrict__ eval_from,
    const float* __restrict__ emb,
    const int* __restrict__ lengths, const int* __restrict__ maxlen,
    float* __restrict__ mean_emb, float* __restrict__ mask_out)
{
    int bid = blockIdx.x;            // b*16 + s
    int b = bid >> 4, s = bid & 15;
    int tid = threadIdx.x;
    __shared__ int seqs[TT];
    __shared__ int msk[TT];
    int ml  = maxlen[s];
    int len = lengths[bid];
    int ef  = eval_from[b];
    if (tid < TT) {
        int v;
        if (tid == 0) v = BOS_ID;
        else { int it = item_id[bid * II + tid - 1]; v = it > 0 ? it : 0; }
        if (tid > ml) v = 0;
        int m = (v != 0) && !(tid == len && len > 0);
        seqs[tid] = v;
        msk[tid]  = m;
        mask_out[bid * TT + tid] = (m && (s >= ef)) ? 1.0f : 0.0f;
    }
    __syncthreads();
    int cnt = 0;
    for (int p = 0; p < TT; ++p) cnt += msk[p];
    float acc = 0.0f;
    int d = tid;
    for (int p = 0; p < TT; ++p) {
        if (msk[p]) acc += emb[seqs[p] * DD + d];
    }
    mean_emb[bid * DD + d] = acc / (float)max(cnt, 1);
}

// ============ kernel 3: GRU chain + hB ============
__global__ __launch_bounds__(128) void gru_kernel(
    const float* __restrict__ me_all,
    const float* __restrict__ wih, const float* __restrict__ whh,
    const float* __restrict__ bih, const float* __restrict__ bhh,
    const float* __restrict__ fus_w, const float* __restrict__ fus_b,
    float* __restrict__ hB)
{
    int b = blockIdx.x;      // 256 blocks
    int j = threadIdx.x;     // 128 threads
    __shared__ __align__(16) float h[DD];
    __shared__ __align__(16) float me[DD];
    h[j] = 0.0f;
    float bihr = bih[j], bihz = bih[128 + j], bihn = bih[256 + j];
    float bhhr = bhh[j], bhhz = bhh[128 + j], bhhn = bhh[256 + j];
    float fb = fus_b[j];
    const float* wr = wih + j * DD;
    const float* wz = wih + (128 + j) * DD;
    const float* wn = wih + (256 + j) * DD;
    const float* vr = whh + j * DD;
    const float* vz = whh + (128 + j) * DD;
    const float* vn = whh + (256 + j) * DD;
    const float* fw = fus_w + j * 256 + 128;
    for (int s = 0; s < SS; ++s) {
        me[j] = me_all[(b * SS + s) * DD + j];
        __syncthreads();
        float hb = fb;
        float xr = bihr, xz = bihz, xn = bihn;
        float hr = bhhr, hz = bhhz, hn = bhhn;
        for (int d = 0; d < DD; d += 4) {
            float4 m4 = *(const float4*)&me[d];
            float4 h4 = *(const float4*)&h[d];
            float4 a;
            a = *(const float4*)&wr[d]; xr += a.x*m4.x + a.y*m4.y + a.z*m4.z + a.w*m4.w;
            a = *(const float4*)&wz[d]; xz += a.x*m4.x + a.y*m4.y + a.z*m4.z + a.w*m4.w;
            a = *(const float4*)&wn[d]; xn += a.x*m4.x + a.y*m4.y + a.z*m4.z + a.w*m4.w;
            a = *(const float4*)&vr[d]; hr += a.x*h4.x + a.y*h4.y + a.z*h4.z + a.w*h4.w;
            a = *(const float4*)&vz[d]; hz += a.x*h4.x + a.y*h4.y + a.z*h4.z + a.w*h4.w;
            a = *(const float4*)&vn[d]; hn += a.x*h4.x + a.y*h4.y + a.z*h4.z + a.w*h4.w;
            a = *(const float4*)&fw[d]; hb += a.x*h4.x + a.y*h4.y + a.z*h4.z + a.w*h4.w;
        }
        hB[(s * BB + b) * DD + j] = hb;   // h BEFORE update (matches reference)
        float r = 1.0f / (1.0f + expf(-(xr + hr)));
        float z = 1.0f / (1.0f + expf(-(xz + hz)));
        float n = tanhf(xn + r * hn);
        float hnew = (1.0f - z) * n + z * h[j];
        __syncthreads();
        h[j] = hnew;
    }
}

// ============ kernel 4: TCN (3 dilated causal convs) + fusion ============
__global__ __launch_bounds__(256) void tcn_kernel(
    const int* __restrict__ item_id, const float* __restrict__ emb,
    const int* __restrict__ lengths, const int* __restrict__ maxlen,
    const float* __restrict__ wT_all,
    const float* __restrict__ cb0, const float* __restrict__ cb1,
    const float* __restrict__ cb2,
    const float* __restrict__ fT, const float* __restrict__ hB,
    float* __restrict__ reps)
{
    __shared__ __align__(16) float bufA[TT * DD];
    __shared__ __align__(16) float bufB[TT * DD];
    __shared__ __align__(16) float wlds[3072];
    __shared__ int seqs[TT];
    int tid = threadIdx.x;
    int bid = blockIdx.x;            // b*16 + s
    int b = bid >> 4, s = bid & 15;
    int ml = maxlen[s];

    if (tid < TT) {
        int v;
        if (tid == 0) v = BOS_ID;
        else { int it = item_id[bid * II + tid - 1]; v = it > 0 ? it : 0; }
        if (tid > ml) v = 0;
        seqs[tid] = v;
    }
    __syncthreads();
    {   // gather e -> bufA  (emb[0] row is zero => PAD rows are zero)
        int r = tid >> 7, d = tid & 127;
        for (int i = 0; i < 33; ++i) {
            int p = 2 * i + r;
            if (p < TT) bufA[p * DD + d] = emb[seqs[p] * DD + d];
        }
    }
    __syncthreads();

    int co = tid & 127, tg = tid >> 7;
    float* xb = bufA;
    float* yb = bufB;

    for (int L = 0; L < 3; ++L) {
        int dil = 1 << L;
        const float* wT = wT_all + L * 3 * DD * DD;
        const float* bp = (L == 0) ? cb0 : ((L == 1) ? cb1 : cb2);
        float acc[33];
#pragma unroll
        for (int i = 0; i < 33; ++i) acc[i] = 0.0f;
        for (int ci0 = 0; ci0 < DD; ci0 += 8) {
#pragma unroll
            for (int ii = 0; ii < 12; ++ii) {   // stage wT[k][ci0..ci0+8)[co]
                int f = tid + ii * 256;         // k=f>>10, ci'=(f>>7)&7, co=f&127
                wlds[f] = wT[(((f >> 10) * DD) + ci0 + ((f >> 7) & 7)) * DD + (f & 127)];
            }
            __syncthreads();
#pragma unroll
            for (int k = 0; k < 3; ++k) {
                int off = (2 - k) * dil;
#pragma unroll
                for (int c4 = 0; c4 < 8; c4 += 4) {
                    float w0 = wlds[(k * 8 + c4 + 0) * DD + co];
                    float w1 = wlds[(k * 8 + c4 + 1) * DD + co];
                    float w2 = wlds[(k * 8 + c4 + 2) * DD + co];
                    float w3 = wlds[(k * 8 + c4 + 3) * DD + co];
#pragma unroll
                    for (int i = 0; i < 33; ++i) {
                        int p = 2 * i + tg;
                        int pp = p - off;
                        if (p < TT && pp >= 0) {
                            const float4 xv = *(const float4*)&xb[pp * DD + ci0 + c4];
                            acc[i] += w0 * xv.x;
                            acc[i] += w1 * xv.y;
                            acc[i] += w2 * xv.z;
                            acc[i] += w3 * xv.w;
                        }
                    }
                }
            }
            __syncthreads();
        }
        float bco = bp[co];
#pragma unroll
        for (int i = 0; i < 33; ++i) {
            int p = 2 * i + tg;
            if (p < TT) {
                float v = acc[i] + bco + xb[p * DD + co];   // residual
                yb[p * DD + co] = v > 0.0f ? v : 0.0f;      // relu
            }
        }
        __syncthreads();
        float* t = xb; xb = yb; yb = t;
    }

    // fusion: reps = tc @ fus_wA^T + (h @ fus_wB^T + fus_b), masked by p<=ml
    {
        float acc[33];
#pragma unroll
        for (int i = 0; i < 33; ++i) acc[i] = 0.0f;
        for (int ci0 = 0; ci0 < DD; ci0 += 16) {
#pragma unroll
            for (int ii = 0; ii < 8; ++ii) {    // stage fT[ci0..ci0+16)[j]
                int f = tid + ii * 256;         // ci'=f>>7, j=f&127
                wlds[f] = fT[(ci0 + (f >> 7)) * DD + (f & 127)];
            }
            __syncthreads();
#pragma unroll
            for (int c4 = 0; c4 < 16; c4 += 4) {
                float w0 = wlds[(c4 + 0) * DD + co];
                float w1 = wlds[(c4 + 1) * DD + co];
                float w2 = wlds[(c4 + 2) * DD + co];
                float w3 = wlds[(c4 + 3) * DD + co];
#pragma unroll
                for (int i = 0; i < 33; ++i) {
                    int p = 2 * i + tg;
                    if (p < TT) {
                        const float4 xv = *(const float4*)&xb[p * DD + ci0 + c4];
                        acc[i] += w0 * xv.x;
                        acc[i] += w1 * xv.y;
                        acc[i] += w2 * xv.z;
                        acc[i] += w3 * xv.w;
                    }
                }
            }
            __syncthreads();
        }
        float hbj = hB[(s * BB + b) * DD + co];
#pragma unroll
        for (int i = 0; i < 33; ++i) {
            int p = 2 * i + tg;
            if (p < TT) {
                float v = (p <= ml) ? (acc[i] + hbj) : 0.0f;
                reps[(long)bid * (TT * DD) + p * DD + co] = v;
            }
        }
    }
}

extern "C" void kernel_launch(void* const* d_in, const int* in_sizes, int n_in,
                              void* d_out, int out_size, void* d_ws, size_t ws_size,
                              hipStream_t stream) {
    const int*   item_id   = (const int*)  d_in[0];
    const int*   eval_from = (const int*)  d_in[1];
    const int*   u_type    = (const int*)  d_in[2];
    const float* emb       = (const float*)d_in[3];
    const float* conv_w0   = (const float*)d_in[4];
    const float* conv_b0   = (const float*)d_in[5];
    const float* conv_w1   = (const float*)d_in[6];
    const float* conv_b1   = (const float*)d_in[7];
    const float* conv_w2   = (const float*)d_in[8];
    const float* conv_b2   = (const float*)d_in[9];
    const float* gru_wih   = (const float*)d_in[10];
    const float* gru_whh   = (const float*)d_in[11];
    const float* gru_bih   = (const float*)d_in[12];
    const float* gru_bhh   = (const float*)d_in[13];
    const float* fus_w     = (const float*)d_in[14];
    const float* fus_b     = (const float*)d_in[15];

    char* ws = (char*)d_ws;
    int*   lengths  = (int*)  (ws + OFF_LEN);
    int*   maxlen   = (int*)  (ws + OFF_ML);
    float* mean_emb = (float*)(ws + OFF_ME);
    float* hB       = (float*)(ws + OFF_HB);
    float* wT       = (float*)(ws + OFF_WT);
    float* fT       = (float*)(ws + OFF_FT);

    float* out   = (float*)d_out;
    float* reps  = out + OUT_REPS;
    float* mout  = out + OUT_MASK;
    float* uout  = out + OUT_UTYPE;

    prep_kernel<<<640, 256, 0, stream>>>(conv_w0, conv_w1, conv_w2, fus_w, wT, fT);
    len_kernel<<<SS, 256, 0, stream>>>(item_id, u_type, lengths, maxlen, uout);
    mean_kernel<<<BB * SS, 128, 0, stream>>>(item_id, eval_from, emb, lengths, maxlen,
                                             mean_emb, mout);
    gru_kernel<<<BB, 128, 0, stream>>>(mean_emb, gru_wih, gru_whh, gru_bih, gru_bhh,
                                       fus_w, fus_b, hB);
    tcn_kernel<<<BB * SS, 256, 0, stream>>>(item_id, emb, lengths, maxlen, wT,
                                            conv_b0, conv_b1, conv_b2, fT, hB, reps);
}

// Round 2
// 495.317 us; speedup vs baseline: 87.0472x; 87.0472x over previous
//
#include <hip/hip_runtime.h>

#define BB 256
#define SS 16
#define II 64
#define DD 128
#define TT 65            // I + 1 (BOS prepended)
#define BOS_ID 100000
#define RB 88            // LDS x-buffer rows: 8 zero guard rows + 80 (5 M-tiles)
#define XBYTES (RB*256)  // 22528 bytes per x buffer (128 bf16 per row = 256 B)

// ---------------- ws layout (bytes) ----------------
#define OFF_LEN 0                        // int lengths[B][S]            16384
#define OFF_ML  16384                    // int maxlen[S]                64
#define OFF_ME  32768                    // float mean_emb[B][S][D]      2 MB
#define OFF_HB  (32768 + 2097152)        // float hB[S][B][D]            2 MB
#define OFF_WB  (OFF_HB + 2097152)       // bf16 wB[3][3][128co][128ci'] 294912 (pre-swizzled)
#define OFF_FT  (OFF_WB + 294912)        // bf16 fT[128j][128ci']        32768  (pre-swizzled)

// ---------------- out layout (float elements) ----------------
#define OUT_MASK  (BB*SS*TT*DD)          // 34,078,720
#define OUT_UTYPE (OUT_MASK + BB*SS*TT)

typedef __attribute__((ext_vector_type(8))) short short8;
typedef __attribute__((ext_vector_type(4))) float f32x4;

__device__ __forceinline__ unsigned short f2bf(float f) {
    unsigned int u = __builtin_bit_cast(unsigned int, f);
    return (unsigned short)((u + 0x7fffu + ((u >> 16) & 1u)) >> 16);  // RNE
}
__device__ __forceinline__ float bf2f(unsigned short h) {
    unsigned int u = ((unsigned int)h) << 16;
    return __builtin_bit_cast(float, u);
}
__device__ __forceinline__ void gld16(const void* g, void* l) {
    __builtin_amdgcn_global_load_lds(
        (const __attribute__((address_space(1))) void*)g,
        (__attribute__((address_space(3))) void*)l, 16, 0, 0);
}

// ============ kernel 0: weight prep (f32 -> bf16, transpose, pre-swizzle) ============
// conv weights OIH [co][ci][k] -> wB[L][k][co][ci ^ ((co&7)<<3)] bf16
// fus_w [j][2D] (tc half) -> fT[j][ci ^ ((j&7)<<3)] bf16
__global__ __launch_bounds__(256) void prep_kernel(
    const float* __restrict__ w0, const float* __restrict__ w1,
    const float* __restrict__ w2, const float* __restrict__ fus_w,
    unsigned short* __restrict__ wB, unsigned short* __restrict__ fT)
{
    int idx = blockIdx.x * 256 + threadIdx.x;
    if (idx < 147456) {
        int L  = idx / 49152;
        int r  = idx % 49152;
        int k  = r >> 14;
        int co = (r >> 7) & 127;
        int ci = r & 127;
        const float* w = (L == 0) ? w0 : ((L == 1) ? w1 : w2);
        float v = w[(co * 128 + ci) * 3 + k];
        wB[((L * 3 + k) * 128 + co) * 128 + (ci ^ ((co & 7) << 3))] = f2bf(v);
    } else if (idx < 147456 + 16384) {
        int f  = idx - 147456;
        int j  = f >> 7;
        int ci = f & 127;
        fT[(j << 7) | (ci ^ ((j & 7) << 3))] = f2bf(fus_w[j * 256 + ci]);
    }
}

// ============ kernel 1: lengths, per-s max, u_type ============
__global__ __launch_bounds__(256) void len_kernel(
    const int* __restrict__ item_id, const int* __restrict__ u_type,
    int* __restrict__ lengths, int* __restrict__ maxlen,
    float* __restrict__ u_out)
{
    int s = blockIdx.x;
    int b = threadIdx.x;
    const int* row = item_id + (b * SS + s) * II;
    int cnt = 0;
    for (int i = 0; i < II; ++i) cnt += (row[i] > 0);
    lengths[b * SS + s] = cnt;
    __shared__ int red[256];
    red[b] = cnt;
    __syncthreads();
    for (int off = 128; off > 0; off >>= 1) {
        if (b < off) red[b] = max(red[b], red[b + off]);
        __syncthreads();
    }
    if (b == 0) maxlen[s] = red[0];
    if (s == 0) u_out[b] = (float)u_type[b];
}

// ============ kernel 2: masks + mean_emb ============
__global__ __launch_bounds__(128) void mean_kernel(
    const int* __restrict__ item_id, const int* __restrict__ eval_from,
    const float* __restrict__ emb,
    const int* __restrict__ lengths, const int* __restrict__ maxlen,
    float* __restrict__ mean_emb, float* __restrict__ mask_out)
{
    int bid = blockIdx.x;
    int b = bid >> 4, s = bid & 15;
    int tid = threadIdx.x;
    __shared__ int seqs[TT];
    __shared__ int msk[TT];
    int ml  = maxlen[s];
    int len = lengths[bid];
    int ef  = eval_from[b];
    if (tid < TT) {
        int v;
        if (tid == 0) v = BOS_ID;
        else { int it = item_id[bid * II + tid - 1]; v = it > 0 ? it : 0; }
        if (tid > ml) v = 0;
        int m = (v != 0) && !(tid == len && len > 0);
        seqs[tid] = v;
        msk[tid]  = m;
        mask_out[bid * TT + tid] = (m && (s >= ef)) ? 1.0f : 0.0f;
    }
    __syncthreads();
    int cnt = 0;
    for (int p = 0; p < TT; ++p) cnt += msk[p];
    float acc = 0.0f;
    int d = tid;
    for (int p = 0; p < TT; ++p) {
        if (msk[p]) acc += emb[seqs[p] * DD + d];
    }
    mean_emb[bid * DD + d] = acc / (float)max(cnt, 1);
}

// ============ kernel 3: GRU chain + hB (f32, tiny) ============
__global__ __launch_bounds__(128) void gru_kernel(
    const float* __restrict__ me_all,
    const float* __restrict__ wih, const float* __restrict__ whh,
    const float* __restrict__ bih, const float* __restrict__ bhh,
    const float* __restrict__ fus_w, const float* __restrict__ fus_b,
    float* __restrict__ hB)
{
    int b = blockIdx.x;
    int j = threadIdx.x;
    __shared__ __align__(16) float h[DD];
    __shared__ __align__(16) float me[DD];
    h[j] = 0.0f;
    float bihr = bih[j], bihz = bih[128 + j], bihn = bih[256 + j];
    float bhhr = bhh[j], bhhz = bhh[128 + j], bhhn = bhh[256 + j];
    float fb = fus_b[j];
    const float* wr = wih + j * DD;
    const float* wz = wih + (128 + j) * DD;
    const float* wn = wih + (256 + j) * DD;
    const float* vr = whh + j * DD;
    const float* vz = whh + (128 + j) * DD;
    const float* vn = whh + (256 + j) * DD;
    const float* fw = fus_w + j * 256 + 128;
    for (int s = 0; s < SS; ++s) {
        me[j] = me_all[(b * SS + s) * DD + j];
        __syncthreads();
        float hb = fb;
        float xr = bihr, xz = bihz, xn = bihn;
        float hr = bhhr, hz = bhhz, hn = bhhn;
        for (int d = 0; d < DD; d += 4) {
            float4 m4 = *(const float4*)&me[d];
            float4 h4 = *(const float4*)&h[d];
            float4 a;
            a = *(const float4*)&wr[d]; xr += a.x*m4.x + a.y*m4.y + a.z*m4.z + a.w*m4.w;
            a = *(const float4*)&wz[d]; xz += a.x*m4.x + a.y*m4.y + a.z*m4.z + a.w*m4.w;
            a = *(const float4*)&wn[d]; xn += a.x*m4.x + a.y*m4.y + a.z*m4.z + a.w*m4.w;
            a = *(const float4*)&vr[d]; hr += a.x*h4.x + a.y*h4.y + a.z*h4.z + a.w*h4.w;
            a = *(const float4*)&vz[d]; hz += a.x*h4.x + a.y*h4.y + a.z*h4.z + a.w*h4.w;
            a = *(const float4*)&vn[d]; hn += a.x*h4.x + a.y*h4.y + a.z*h4.z + a.w*h4.w;
            a = *(const float4*)&fw[d]; hb += a.x*h4.x + a.y*h4.y + a.z*h4.z + a.w*h4.w;
        }
        hB[(s * BB + b) * DD + j] = hb;   // uses h BEFORE update (matches reference)
        float r = 1.0f / (1.0f + expf(-(xr + hr)));
        float z = 1.0f / (1.0f + expf(-(xz + hz)));
        float n = tanhf(xn + r * hn);
        float hnew = (1.0f - z) * n + z * h[j];
        __syncthreads();
        h[j] = hnew;
    }
}

// ============ kernel 4: MFMA TCN + fusion ============
// One block per (b,s). 4 waves; wave w owns co = [32w, 32w+32), all 65 positions.
// 5 M-tiles x 2 N-tiles of 16x16, K-steps of 32 via mfma_f32_16x16x32_bf16.
__global__ __launch_bounds__(256) void tcn_kernel(
    const int* __restrict__ item_id, const float* __restrict__ emb,
    const int* __restrict__ maxlen,
    const unsigned short* __restrict__ wB,
    const float* __restrict__ cb0, const float* __restrict__ cb1,
    const float* __restrict__ cb2,
    const unsigned short* __restrict__ fT, const float* __restrict__ hB,
    float* __restrict__ reps)
{
    __shared__ __align__(16) unsigned char xbufA[XBYTES];
    __shared__ __align__(16) unsigned char xbufB[XBYTES];
    __shared__ __align__(16) unsigned char wl[32768];
    __shared__ int seqs[TT];

    int tid  = threadIdx.x;
    int bid  = blockIdx.x;              // b*16 + s
    int b    = bid >> 4, s = bid & 15;
    int lane = tid & 63, wv = tid >> 6;
    int ml   = maxlen[s];

    if (tid < TT) {
        int v;
        if (tid == 0) v = BOS_ID;
        else { int it = item_id[bid * II + tid - 1]; v = it > 0 ? it : 0; }
        if (tid > ml) v = 0;
        seqs[tid] = v;
    }
    // zero the 8 guard rows (2048 B) of both buffers
    if (tid < 128) { *(unsigned int*)(xbufA + tid * 16) = 0u;
                     *(unsigned int*)(xbufA + tid * 16 + 4) = 0u;
                     *(unsigned int*)(xbufA + tid * 16 + 8) = 0u;
                     *(unsigned int*)(xbufA + tid * 16 + 12) = 0u; }
    else { int t = tid - 128;
           *(unsigned int*)(xbufB + t * 16) = 0u;
           *(unsigned int*)(xbufB + t * 16 + 4) = 0u;
           *(unsigned int*)(xbufB + t * 16 + 8) = 0u;
           *(unsigned int*)(xbufB + t * 16 + 12) = 0u; }
    __syncthreads();

    // gather embeddings -> xbufA rows 8..72, bf16, XOR-swizzled (byte ^= (row&7)<<4)
    for (int p = wv; p < TT; p += 4) {
        const float* er = emb + (long)seqs[p] * DD + lane * 2;
        float f0 = er[0], f1 = er[1];
        int row = 8 + p;
        unsigned int pk = ((unsigned int)f2bf(f1) << 16) | (unsigned int)f2bf(f0);
        *(unsigned int*)(xbufA + row * 256 + ((lane * 4) ^ ((row & 7) << 4))) = pk;
    }

    unsigned char* xsrc = xbufA;
    unsigned char* ydst = xbufB;
    int co0  = wv * 32;
    int colb = (lane >> 4) * 16;        // byte offset of this lane's 8-bf16 K-subgroup

    f32x4 acc[5][2];

    for (int L = 0; L < 3; ++L) {
        int dil = 1 << L;
        const float* cb = (L == 0) ? cb0 : ((L == 1) ? cb1 : cb2);
#pragma unroll
        for (int mt = 0; mt < 5; ++mt)
#pragma unroll
            for (int nt = 0; nt < 2; ++nt)
#pragma unroll
                for (int r = 0; r < 4; ++r) acc[mt][nt][r] = 0.0f;

        for (int k = 0; k < 3; ++k) {
            __syncthreads();            // wl free, x buffer ready
            {   // stage wB[L][k] (32 KB, pre-swizzled) linearly into wl
                const unsigned char* g =
                    (const unsigned char*)wB + (size_t)(L * 3 + k) * 32768 +
                    (wv * 64 + lane) * 16;
#pragma unroll
                for (int i = 0; i < 8; ++i)
                    gld16(g + i * 4096, wl + wv * 1024 + i * 4096);
            }
            asm volatile("s_waitcnt vmcnt(0)" ::: "memory");
            __syncthreads();

            int off = (2 - k) * dil;
#pragma unroll
            for (int cib = 0; cib < 4; ++cib) {
                int cbyte = cib * 64 + colb;
                short8 bfr[2];
#pragma unroll
                for (int nt = 0; nt < 2; ++nt) {
                    int rowB = co0 + nt * 16 + (lane & 15);
                    bfr[nt] = *(const short8*)(wl + rowB * 256 +
                                               (cbyte ^ ((rowB & 7) << 4)));
                }
#pragma unroll
                for (int mt = 0; mt < 5; ++mt) {
                    int rowA = 8 + mt * 16 + (lane & 15) - off;
                    short8 af = *(const short8*)(xsrc + rowA * 256 +
                                                 (cbyte ^ ((rowA & 7) << 4)));
                    acc[mt][0] = __builtin_amdgcn_mfma_f32_16x16x32_bf16(
                        af, bfr[0], acc[mt][0], 0, 0, 0);
                    acc[mt][1] = __builtin_amdgcn_mfma_f32_16x16x32_bf16(
                        af, bfr[1], acc[mt][1], 0, 0, 0);
                }
            }
        }
        // epilogue: y = relu(acc + bias + residual) -> ydst (bf16, swizzled)
        float bias0 = cb[co0 + (lane & 15)];
        float bias1 = cb[co0 + 16 + (lane & 15)];
#pragma unroll
        for (int mt = 0; mt < 5; ++mt)
#pragma unroll
            for (int nt = 0; nt < 2; ++nt) {
                int co = co0 + nt * 16 + (lane & 15);
                float bia = nt ? bias1 : bias0;
#pragma unroll
                for (int r = 0; r < 4; ++r) {
                    int p = mt * 16 + (lane >> 4) * 4 + r;
                    if (p < TT) {
                        int row = 8 + p;
                        int xb2 = row * 256 + ((co * 2) ^ ((row & 7) << 4));
                        float v = acc[mt][nt][r] + bia +
                                  bf2f(*(const unsigned short*)(xsrc + xb2));
                        *(unsigned short*)(ydst + xb2) = f2bf(v > 0.f ? v : 0.f);
                    }
                }
            }
        unsigned char* t = xsrc; xsrc = ydst; ydst = t;
    }

    // ---- fusion: reps[p][j] = (p<=ml) ? tc[p]·fus_wA[j] + hB[j] : 0 ----
    __syncthreads();                    // wl free, tc (xsrc) ready
    {
        const unsigned char* g = (const unsigned char*)fT + (wv * 64 + lane) * 16;
#pragma unroll
        for (int i = 0; i < 8; ++i)
            gld16(g + i * 4096, wl + wv * 1024 + i * 4096);
    }
    asm volatile("s_waitcnt vmcnt(0)" ::: "memory");
    __syncthreads();

#pragma unroll
    for (int mt = 0; mt < 5; ++mt)
#pragma unroll
        for (int nt = 0; nt < 2; ++nt)
#pragma unroll
            for (int r = 0; r < 4; ++r) acc[mt][nt][r] = 0.0f;

#pragma unroll
    for (int cib = 0; cib < 4; ++cib) {
        int cbyte = cib * 64 + colb;
        short8 bfr[2];
#pragma unroll
        for (int nt = 0; nt < 2; ++nt) {
            int rowB = co0 + nt * 16 + (lane & 15);
            bfr[nt] = *(const short8*)(wl + rowB * 256 + (cbyte ^ ((rowB & 7) << 4)));
        }
#pragma unroll
        for (int mt = 0; mt < 5; ++mt) {
            int rowA = 8 + mt * 16 + (lane & 15);
            short8 af = *(const short8*)(xsrc + rowA * 256 +
                                         (cbyte ^ ((rowA & 7) << 4)));
            acc[mt][0] = __builtin_amdgcn_mfma_f32_16x16x32_bf16(
                af, bfr[0], acc[mt][0], 0, 0, 0);
            acc[mt][1] = __builtin_amdgcn_mfma_f32_16x16x32_bf16(
                af, bfr[1], acc[mt][1], 0, 0, 0);
        }
    }

    float hb0 = hB[(s * BB + b) * DD + co0 + (lane & 15)];
    float hb1 = hB[(s * BB + b) * DD + co0 + 16 + (lane & 15)];
    long obase = (long)bid * (TT * DD);
#pragma unroll
    for (int mt = 0; mt < 5; ++mt)
#pragma unroll
        for (int nt = 0; nt < 2; ++nt) {
            int j = co0 + nt * 16 + (lane & 15);
            float hb = nt ? hb1 : hb0;
#pragma unroll
            for (int r = 0; r < 4; ++r) {
                int p = mt * 16 + (lane >> 4) * 4 + r;
                if (p < TT) {
                    float v = (p <= ml) ? (acc[mt][nt][r] + hb) : 0.0f;
                    reps[obase + p * DD + j] = v;
                }
            }
        }
}

extern "C" void kernel_launch(void* const* d_in, const int* in_sizes, int n_in,
                              void* d_out, int out_size, void* d_ws, size_t ws_size,
                              hipStream_t stream) {
    const int*   item_id   = (const int*)  d_in[0];
    const int*   eval_from = (const int*)  d_in[1];
    const int*   u_type    = (const int*)  d_in[2];
    const float* emb       = (const float*)d_in[3];
    const float* conv_w0   = (const float*)d_in[4];
    const float* conv_b0   = (const float*)d_in[5];
    const float* conv_w1   = (const float*)d_in[6];
    const float* conv_b1   = (const float*)d_in[7];
    const float* conv_w2   = (const float*)d_in[8];
    const float* conv_b2   = (const float*)d_in[9];
    const float* gru_wih   = (const float*)d_in[10];
    const float* gru_whh   = (const float*)d_in[11];
    const float* gru_bih   = (const float*)d_in[12];
    const float* gru_bhh   = (const float*)d_in[13];
    const float* fus_w     = (const float*)d_in[14];
    const float* fus_b     = (const float*)d_in[15];

    char* ws = (char*)d_ws;
    int*            lengths  = (int*)           (ws + OFF_LEN);
    int*            maxlen   = (int*)           (ws + OFF_ML);
    float*          mean_emb = (float*)         (ws + OFF_ME);
    float*          hB       = (float*)         (ws + OFF_HB);
    unsigned short* wB       = (unsigned short*)(ws + OFF_WB);
    unsigned short* fT       = (unsigned short*)(ws + OFF_FT);

    float* out  = (float*)d_out;
    float* reps = out;
    float* mout = out + OUT_MASK;
    float* uout = out + OUT_UTYPE;

    prep_kernel<<<640, 256, 0, stream>>>(conv_w0, conv_w1, conv_w2, fus_w, wB, fT);
    len_kernel<<<SS, 256, 0, stream>>>(item_id, u_type, lengths, maxlen, uout);
    mean_kernel<<<BB * SS, 128, 0, stream>>>(item_id, eval_from, emb, lengths, maxlen,
                                             mean_emb, mout);
    gru_kernel<<<BB, 128, 0, stream>>>(mean_emb, gru_wih, gru_whh, gru_bih, gru_bhh,
                                       fus_w, fus_b, hB);
    tcn_kernel<<<BB * SS, 256, 0, stream>>>(item_id, emb, maxlen, wB,
                                            conv_b0, conv_b1, conv_b2, fT, hB, reps);
}

// Round 3
// 292.590 us; speedup vs baseline: 147.3595x; 1.6929x over previous
//
#include <hip/hip_runtime.h>

#define BB 256
#define SS 16
#define II 64
#define DD 128
#define TT 65            // I + 1 (BOS prepended)
#define BOS_ID 100000
#define RB 88            // LDS x-buffer rows: 8 zero guard rows + 80 (5 M-tiles)
#define XBYTES (RB*256)  // 22528 bytes per x buffer (128 bf16 per row = 256 B)

// ---------------- ws layout (bytes) ----------------
#define OFF_LEN  0                        // int lengths[B][S]            16384
#define OFF_ML   16384                    // int maxlen[S]                64
#define OFF_ME   32768                    // float mean_emb[B][S][D]      2 MB
#define OFF_HB   (32768 + 2097152)        // float hB[S][B][D]            2 MB
#define OFF_WB   (OFF_HB + 2097152)       // bf16 wB[3][3][128co][128ci'] 294912 (pre-swizzled)
#define OFF_FT   (OFF_WB + 294912)        // bf16 fT[128j][128ci']        32768  (pre-swizzled)
#define OFF_WIHP (OFF_FT + 32768)         // u32 wihP[64][384]            98304
#define OFF_WGRU (OFF_WIHP + 98304)       // u32 wgruP[64][512]           131072
#define OFF_GI   (OFF_WGRU + 131072)      // float gi[4096][384]          6291456

// ---------------- out layout (float elements) ----------------
#define OUT_MASK  (BB*SS*TT*DD)          // 34,078,720
#define OUT_UTYPE (OUT_MASK + BB*SS*TT)

typedef __attribute__((ext_vector_type(8))) short short8;
typedef __attribute__((ext_vector_type(4))) float f32x4;

__device__ __forceinline__ unsigned short f2bf(float f) {
    unsigned int u = __builtin_bit_cast(unsigned int, f);
    return (unsigned short)((u + 0x7fffu + ((u >> 16) & 1u)) >> 16);  // RNE
}
__device__ __forceinline__ float bf2f(unsigned short h) {
    unsigned int u = ((unsigned int)h) << 16;
    return __builtin_bit_cast(float, u);
}
__device__ __forceinline__ void gld16(const void* g, void* l) {
    __builtin_amdgcn_global_load_lds(
        (const __attribute__((address_space(1))) void*)g,
        (__attribute__((address_space(3))) void*)l, 16, 0, 0);
}

// ============ kernel 0: weight prep ============
// conv OIH -> wB[L][k][co][ci^((co&7)<<3)] bf16 (pre-swizzled for tcn)
// fus_w tc-half -> fT[j][ci^((j&7)<<3)] bf16
// wih  -> wihP[dd][r]  = pack_bf16(wih[r][2dd], wih[r][2dd+1])        r in [0,384)
// whh/fusB -> wgruP[dd][r]: r<384 from whh[r], r>=384 from fus_w[r-384][128+..]
__global__ __launch_bounds__(256) void prep_kernel(
    const float* __restrict__ w0, const float* __restrict__ w1,
    const float* __restrict__ w2, const float* __restrict__ fus_w,
    const float* __restrict__ wih, const float* __restrict__ whh,
    unsigned short* __restrict__ wB, unsigned short* __restrict__ fT,
    unsigned int* __restrict__ wihP, unsigned int* __restrict__ wgruP)
{
    int idx = blockIdx.x * 256 + threadIdx.x;
    if (idx < 147456) {
        int L  = idx / 49152;
        int r  = idx % 49152;
        int k  = r >> 14;
        int co = (r >> 7) & 127;
        int ci = r & 127;
        const float* w = (L == 0) ? w0 : ((L == 1) ? w1 : w2);
        float v = w[(co * 128 + ci) * 3 + k];
        wB[((L * 3 + k) * 128 + co) * 128 + (ci ^ ((co & 7) << 3))] = f2bf(v);
    } else if (idx < 163840) {
        int f  = idx - 147456;
        int j  = f >> 7;
        int ci = f & 127;
        fT[(j << 7) | (ci ^ ((j & 7) << 3))] = f2bf(fus_w[j * 256 + ci]);
    } else if (idx < 163840 + 24576) {
        int f  = idx - 163840;
        int dd = f / 384;
        int r  = f % 384;
        unsigned int lo = f2bf(wih[r * 128 + 2 * dd]);
        unsigned int hi = f2bf(wih[r * 128 + 2 * dd + 1]);
        wihP[f] = (hi << 16) | lo;
    } else if (idx < 163840 + 24576 + 32768) {
        int f  = idx - 163840 - 24576;
        int dd = f >> 9;
        int r  = f & 511;
        float v0, v1;
        if (r < 384) { v0 = whh[r * 128 + 2 * dd]; v1 = whh[r * 128 + 2 * dd + 1]; }
        else { const float* fw = fus_w + (r - 384) * 256 + 128;
               v0 = fw[2 * dd]; v1 = fw[2 * dd + 1]; }
        wgruP[f] = ((unsigned int)f2bf(v1) << 16) | (unsigned int)f2bf(v0);
    }
}

// ============ kernel 1: lengths, per-s max, u_type ============
__global__ __launch_bounds__(256) void len_kernel(
    const int* __restrict__ item_id, const int* __restrict__ u_type,
    int* __restrict__ lengths, int* __restrict__ maxlen,
    float* __restrict__ u_out)
{
    int s = blockIdx.x;
    int b = threadIdx.x;
    const int* row = item_id + (b * SS + s) * II;
    int cnt = 0;
    for (int i = 0; i < II; ++i) cnt += (row[i] > 0);
    lengths[b * SS + s] = cnt;
    __shared__ int red[256];
    red[b] = cnt;
    __syncthreads();
    for (int off = 128; off > 0; off >>= 1) {
        if (b < off) red[b] = max(red[b], red[b + off]);
        __syncthreads();
    }
    if (b == 0) maxlen[s] = red[0];
    if (s == 0) u_out[b] = (float)u_type[b];
}

// ============ kernel 2: masks + mean_emb ============
__global__ __launch_bounds__(128) void mean_kernel(
    const int* __restrict__ item_id, const int* __restrict__ eval_from,
    const float* __restrict__ emb,
    const int* __restrict__ lengths, const int* __restrict__ maxlen,
    float* __restrict__ mean_emb, float* __restrict__ mask_out)
{
    int bid = blockIdx.x;
    int b = bid >> 4, s = bid & 15;
    int tid = threadIdx.x;
    __shared__ int seqs[TT];
    __shared__ int msk[TT];
    int ml  = maxlen[s];
    int len = lengths[bid];
    int ef  = eval_from[b];
    if (tid < TT) {
        int v;
        if (tid == 0) v = BOS_ID;
        else { int it = item_id[bid * II + tid - 1]; v = it > 0 ? it : 0; }
        if (tid > ml) v = 0;
        int m = (v != 0) && !(tid == len && len > 0);
        seqs[tid] = v;
        msk[tid]  = m;
        mask_out[bid * TT + tid] = (m && (s >= ef)) ? 1.0f : 0.0f;
    }
    __syncthreads();
    int cnt = 0;
    for (int p = 0; p < TT; ++p) cnt += msk[p];
    float acc = 0.0f;
    int d = tid;
    for (int p = 0; p < TT; ++p) {
        if (msk[p]) acc += emb[seqs[p] * DD + d];
    }
    mean_emb[bid * DD + d] = acc / (float)max(cnt, 1);
}

// ============ kernel 3a: gi = me @ wih^T + bih (parallel over all b,s) ============
__global__ __launch_bounds__(384, 1) void gi_kernel(
    const float* __restrict__ me_all, const unsigned int* __restrict__ wihP,
    const float* __restrict__ bih, float* __restrict__ gi_all)
{
    __shared__ __align__(16) unsigned int wl[64 * 384];   // 96 KB
    __shared__ __align__(16) float me[DD];
    int t   = threadIdx.x;
    int blk = blockIdx.x;
    {
        const unsigned char* g = (const unsigned char*)wihP + t * 16;
        unsigned char* l = (unsigned char*)wl + t * 16;
#pragma unroll
        for (int i = 0; i < 16; ++i) gld16(g + i * 6144, l + i * 6144);
    }
    float bi = bih[t];
    asm volatile("s_waitcnt vmcnt(0)" ::: "memory");
    __syncthreads();
    for (int q = 0; q < 16; ++q) {
        int bs = blk * 16 + q;
        if (t < DD) me[t] = me_all[bs * DD + t];
        __syncthreads();
        float acc = bi;
#pragma unroll
        for (int dd = 0; dd < 64; ++dd) {
            unsigned int u = wl[dd * 384 + t];
            float f0 = __builtin_bit_cast(float, u << 16);
            float f1 = __builtin_bit_cast(float, u & 0xffff0000u);
            acc += f0 * me[2 * dd] + f1 * me[2 * dd + 1];
        }
        gi_all[bs * 384 + t] = acc;
        __syncthreads();
    }
}

// ============ kernel 3b: sequential GRU (gh, hb) with LDS-resident weights ============
// 512 threads: t<384 -> gh row t (whh), t>=384 -> hb row t-384 (fusB half).
__global__ __launch_bounds__(512, 1) void gru_kernel(
    const unsigned int* __restrict__ wgruP, const float* __restrict__ bhh,
    const float* __restrict__ fus_b, const float* __restrict__ gi_all,
    float* __restrict__ hB)
{
    __shared__ __align__(16) unsigned int wl[64 * 512];   // 128 KB
    __shared__ float h[DD];
    __shared__ float g_z[DD], g_inn[DD], g_hn[DD];
    int t = threadIdx.x;
    int b = blockIdx.x;
    int j = t & 127;
    int grp = t >> 7;      // 0=r, 1=z, 2=n, 3=hb
    {
        const unsigned char* g = (const unsigned char*)wgruP + t * 16;
        unsigned char* l = (unsigned char*)wl + t * 16;
#pragma unroll
        for (int i = 0; i < 16; ++i) gld16(g + i * 8192, l + i * 8192);
    }
    float bias = (t < 384) ? bhh[t] : fus_b[j];
    if (t < DD) h[t] = 0.0f;
    asm volatile("s_waitcnt vmcnt(0)" ::: "memory");
    __syncthreads();
    for (int s = 0; s < SS; ++s) {
        float gi = (grp < 3) ? gi_all[(b * SS + s) * 384 + t] : 0.0f;
        float acc = bias;
#pragma unroll
        for (int dd = 0; dd < 64; ++dd) {
            unsigned int u = wl[dd * 512 + t];
            float f0 = __builtin_bit_cast(float, u << 16);
            float f1 = __builtin_bit_cast(float, u & 0xffff0000u);
            acc += f0 * h[2 * dd] + f1 * h[2 * dd + 1];
        }
        if (grp == 3) {
            hB[(s * BB + b) * DD + j] = acc;          // h BEFORE update; fus_b included
        } else if (grp == 1) { g_z[j] = gi + acc; }
        else if (grp == 2)   { g_inn[j] = gi; g_hn[j] = acc; }
        __syncthreads();
        if (grp == 0) {
            float r = 1.0f / (1.0f + expf(-(gi + acc)));
            float z = 1.0f / (1.0f + expf(-g_z[j]));
            float n = tanhf(g_inn[j] + r * g_hn[j]);
            h[j] = (1.0f - z) * n + z * h[j];
        }
        __syncthreads();
    }
}

// ============ kernel 4: MFMA TCN + fusion ============
__global__ __launch_bounds__(256) void tcn_kernel(
    const int* __restrict__ item_id, const float* __restrict__ emb,
    const int* __restrict__ maxlen,
    const unsigned short* __restrict__ wB,
    const float* __restrict__ cb0, const float* __restrict__ cb1,
    const float* __restrict__ cb2,
    const unsigned short* __restrict__ fT, const float* __restrict__ hB,
    float* __restrict__ reps)
{
    __shared__ __align__(16) unsigned char xbufA[XBYTES];
    __shared__ __align__(16) unsigned char xbufB[XBYTES];
    __shared__ __align__(16) unsigned char wl[32768];
    __shared__ int seqs[TT];

    int tid  = threadIdx.x;
    int bid  = blockIdx.x;              // b*16 + s
    int b    = bid >> 4, s = bid & 15;
    int lane = tid & 63, wv = tid >> 6;
    int ml   = maxlen[s];

    if (tid < TT) {
        int v;
        if (tid == 0) v = BOS_ID;
        else { int it = item_id[bid * II + tid - 1]; v = it > 0 ? it : 0; }
        if (tid > ml) v = 0;
        seqs[tid] = v;
    }
    if (tid < 128) { *(unsigned int*)(xbufA + tid * 16) = 0u;
                     *(unsigned int*)(xbufA + tid * 16 + 4) = 0u;
                     *(unsigned int*)(xbufA + tid * 16 + 8) = 0u;
                     *(unsigned int*)(xbufA + tid * 16 + 12) = 0u; }
    else { int t = tid - 128;
           *(unsigned int*)(xbufB + t * 16) = 0u;
           *(unsigned int*)(xbufB + t * 16 + 4) = 0u;
           *(unsigned int*)(xbufB + t * 16 + 8) = 0u;
           *(unsigned int*)(xbufB + t * 16 + 12) = 0u; }
    __syncthreads();

    for (int p = wv; p < TT; p += 4) {
        const float* er = emb + (long)seqs[p] * DD + lane * 2;
        float f0 = er[0], f1 = er[1];
        int row = 8 + p;
        unsigned int pk = ((unsigned int)f2bf(f1) << 16) | (unsigned int)f2bf(f0);
        *(unsigned int*)(xbufA + row * 256 + ((lane * 4) ^ ((row & 7) << 4))) = pk;
    }

    unsigned char* xsrc = xbufA;
    unsigned char* ydst = xbufB;
    int co0  = wv * 32;
    int colb = (lane >> 4) * 16;

    f32x4 acc[5][2];

    for (int L = 0; L < 3; ++L) {
        int dil = 1 << L;
        const float* cb = (L == 0) ? cb0 : ((L == 1) ? cb1 : cb2);
#pragma unroll
        for (int mt = 0; mt < 5; ++mt)
#pragma unroll
            for (int nt = 0; nt < 2; ++nt)
#pragma unroll
                for (int r = 0; r < 4; ++r) acc[mt][nt][r] = 0.0f;

        for (int k = 0; k < 3; ++k) {
            __syncthreads();
            {
                const unsigned char* g =
                    (const unsigned char*)wB + (size_t)(L * 3 + k) * 32768 +
                    (wv * 64 + lane) * 16;
#pragma unroll
                for (int i = 0; i < 8; ++i)
                    gld16(g + i * 4096, wl + wv * 1024 + i * 4096);
            }
            asm volatile("s_waitcnt vmcnt(0)" ::: "memory");
            __syncthreads();

            int off = (2 - k) * dil;
#pragma unroll
            for (int cib = 0; cib < 4; ++cib) {
                int cbyte = cib * 64 + colb;
                short8 bfr[2];
#pragma unroll
                for (int nt = 0; nt < 2; ++nt) {
                    int rowB = co0 + nt * 16 + (lane & 15);
                    bfr[nt] = *(const short8*)(wl + rowB * 256 +
                                               (cbyte ^ ((rowB & 7) << 4)));
                }
#pragma unroll
                for (int mt = 0; mt < 5; ++mt) {
                    int rowA = 8 + mt * 16 + (lane & 15) - off;
                    short8 af = *(const short8*)(xsrc + rowA * 256 +
                                                 (cbyte ^ ((rowA & 7) << 4)));
                    acc[mt][0] = __builtin_amdgcn_mfma_f32_16x16x32_bf16(
                        af, bfr[0], acc[mt][0], 0, 0, 0);
                    acc[mt][1] = __builtin_amdgcn_mfma_f32_16x16x32_bf16(
                        af, bfr[1], acc[mt][1], 0, 0, 0);
                }
            }
        }
        float bias0 = cb[co0 + (lane & 15)];
        float bias1 = cb[co0 + 16 + (lane & 15)];
#pragma unroll
        for (int mt = 0; mt < 5; ++mt)
#pragma unroll
            for (int nt = 0; nt < 2; ++nt) {
                int co = co0 + nt * 16 + (lane & 15);
                float bia = nt ? bias1 : bias0;
#pragma unroll
                for (int r = 0; r < 4; ++r) {
                    int p = mt * 16 + (lane >> 4) * 4 + r;
                    if (p < TT) {
                        int row = 8 + p;
                        int xb2 = row * 256 + ((co * 2) ^ ((row & 7) << 4));
                        float v = acc[mt][nt][r] + bia +
                                  bf2f(*(const unsigned short*)(xsrc + xb2));
                        *(unsigned short*)(ydst + xb2) = f2bf(v > 0.f ? v : 0.f);
                    }
                }
            }
        unsigned char* t = xsrc; xsrc = ydst; ydst = t;
    }

    __syncthreads();
    {
        const unsigned char* g = (const unsigned char*)fT + (wv * 64 + lane) * 16;
#pragma unroll
        for (int i = 0; i < 8; ++i)
            gld16(g + i * 4096, wl + wv * 1024 + i * 4096);
    }
    asm volatile("s_waitcnt vmcnt(0)" ::: "memory");
    __syncthreads();

#pragma unroll
    for (int mt = 0; mt < 5; ++mt)
#pragma unroll
        for (int nt = 0; nt < 2; ++nt)
#pragma unroll
            for (int r = 0; r < 4; ++r) acc[mt][nt][r] = 0.0f;

#pragma unroll
    for (int cib = 0; cib < 4; ++cib) {
        int cbyte = cib * 64 + colb;
        short8 bfr[2];
#pragma unroll
        for (int nt = 0; nt < 2; ++nt) {
            int rowB = co0 + nt * 16 + (lane & 15);
            bfr[nt] = *(const short8*)(wl + rowB * 256 + (cbyte ^ ((rowB & 7) << 4)));
        }
#pragma unroll
        for (int mt = 0; mt < 5; ++mt) {
            int rowA = 8 + mt * 16 + (lane & 15);
            short8 af = *(const short8*)(xsrc + rowA * 256 +
                                         (cbyte ^ ((rowA & 7) << 4)));
            acc[mt][0] = __builtin_amdgcn_mfma_f32_16x16x32_bf16(
                af, bfr[0], acc[mt][0], 0, 0, 0);
            acc[mt][1] = __builtin_amdgcn_mfma_f32_16x16x32_bf16(
                af, bfr[1], acc[mt][1], 0, 0, 0);
        }
    }

    float hb0 = hB[(s * BB + b) * DD + co0 + (lane & 15)];
    float hb1 = hB[(s * BB + b) * DD + co0 + 16 + (lane & 15)];
    long obase = (long)bid * (TT * DD);
#pragma unroll
    for (int mt = 0; mt < 5; ++mt)
#pragma unroll
        for (int nt = 0; nt < 2; ++nt) {
            int j = co0 + nt * 16 + (lane & 15);
            float hb = nt ? hb1 : hb0;
#pragma unroll
            for (int r = 0; r < 4; ++r) {
                int p = mt * 16 + (lane >> 4) * 4 + r;
                if (p < TT) {
                    float v = (p <= ml) ? (acc[mt][nt][r] + hb) : 0.0f;
                    reps[obase + p * DD + j] = v;
                }
            }
        }
}

extern "C" void kernel_launch(void* const* d_in, const int* in_sizes, int n_in,
                              void* d_out, int out_size, void* d_ws, size_t ws_size,
                              hipStream_t stream) {
    const int*   item_id   = (const int*)  d_in[0];
    const int*   eval_from = (const int*)  d_in[1];
    const int*   u_type    = (const int*)  d_in[2];
    const float* emb       = (const float*)d_in[3];
    const float* conv_w0   = (const float*)d_in[4];
    const float* conv_b0   = (const float*)d_in[5];
    const float* conv_w1   = (const float*)d_in[6];
    const float* conv_b1   = (const float*)d_in[7];
    const float* conv_w2   = (const float*)d_in[8];
    const float* conv_b2   = (const float*)d_in[9];
    const float* gru_wih   = (const float*)d_in[10];
    const float* gru_whh   = (const float*)d_in[11];
    const float* gru_bih   = (const float*)d_in[12];
    const float* gru_bhh   = (const float*)d_in[13];
    const float* fus_w     = (const float*)d_in[14];
    const float* fus_b     = (const float*)d_in[15];

    char* ws = (char*)d_ws;
    int*            lengths  = (int*)           (ws + OFF_LEN);
    int*            maxlen   = (int*)           (ws + OFF_ML);
    float*          mean_emb = (float*)         (ws + OFF_ME);
    float*          hB       = (float*)         (ws + OFF_HB);
    unsigned short* wB       = (unsigned short*)(ws + OFF_WB);
    unsigned short* fT       = (unsigned short*)(ws + OFF_FT);
    unsigned int*   wihP     = (unsigned int*)  (ws + OFF_WIHP);
    unsigned int*   wgruP    = (unsigned int*)  (ws + OFF_WGRU);
    float*          gi_all   = (float*)         (ws + OFF_GI);

    float* out  = (float*)d_out;
    float* reps = out;
    float* mout = out + OUT_MASK;
    float* uout = out + OUT_UTYPE;

    prep_kernel<<<864, 256, 0, stream>>>(conv_w0, conv_w1, conv_w2, fus_w,
                                         gru_wih, gru_whh, wB, fT, wihP, wgruP);
    len_kernel<<<SS, 256, 0, stream>>>(item_id, u_type, lengths, maxlen, uout);
    mean_kernel<<<BB * SS, 128, 0, stream>>>(item_id, eval_from, emb, lengths, maxlen,
                                             mean_emb, mout);
    gi_kernel<<<BB, 384, 0, stream>>>(mean_emb, wihP, gru_bih, gi_all);
    gru_kernel<<<BB, 512, 0, stream>>>(wgruP, gru_bhh, fus_b, gi_all, hB);
    tcn_kernel<<<BB * SS, 256, 0, stream>>>(item_id, emb, maxlen, wB,
                                            conv_b0, conv_b1, conv_b2, fT, hB, reps);
}

// Round 4
// 269.381 us; speedup vs baseline: 160.0556x; 1.0862x over previous
//
#include <hip/hip_runtime.h>

#define BB 256
#define SS 16
#define II 64
#define DD 128
#define TT 65            // I + 1 (BOS prepended)
#define BOS_ID 100000
#define XROW 304         // padded x row stride (256 B data + 48 B pad, 3*row mod 8 bank walk)
#define XROWS 73         // 8 zero guard rows + 65 positions
#define XT (XROWS*XROW)  // 22192 B per tile

// ---------------- ws layout (bytes) ----------------
#define OFF_LEN  0                        // int lengths[B][S]            16384
#define OFF_ML   16384                    // int maxlen[S]                64
#define OFF_ME   32768                    // float mean_emb[B][S][D]      2 MB
#define OFF_HB   (32768 + 2097152)        // float hB[S][B][D]            2 MB
#define OFF_WB2  (OFF_HB + 2097152)       // bf16 wB2[80 chunks][2048]    327680
#define OFF_WIHP (OFF_WB2 + 327680)       // u32 wihP[64][384]            98304
#define OFF_WGRU (OFF_WIHP + 98304)       // u32 wgruP[64][512]           131072
#define OFF_GI   (OFF_WGRU + 131072)      // float gi[4096][384]          6291456

// ---------------- out layout (float elements) ----------------
#define OUT_MASK  (BB*SS*TT*DD)          // 34,078,720
#define OUT_UTYPE (OUT_MASK + BB*SS*TT)

typedef __attribute__((ext_vector_type(8))) short short8;
typedef __attribute__((ext_vector_type(4))) float f32x4;

__device__ __forceinline__ unsigned short f2bf(float f) {
    unsigned int u = __builtin_bit_cast(unsigned int, f);
    return (unsigned short)((u + 0x7fffu + ((u >> 16) & 1u)) >> 16);  // RNE
}
__device__ __forceinline__ float bf2f(unsigned short h) {
    unsigned int u = ((unsigned int)h) << 16;
    return __builtin_bit_cast(float, u);
}
__device__ __forceinline__ void gld16(const void* g, void* l) {
    __builtin_amdgcn_global_load_lds(
        (const __attribute__((address_space(1))) void*)g,
        (__attribute__((address_space(3))) void*)l, 16, 0, 0);
}

// ============ kernel 0: weight prep ============
// Conv + fusion weights -> wB2, 80 chunks of 4 KB, chunk = (cid, nh):
//   cid = (L*3+k)*4+cq for conv (0..35), 36+cq for fusion; nh = co-half.
//   chunk layout [g 0..3][c 0..63][e 0..7] bf16: W[co=nh*64+c][ci=cq*32+g*8+e] (tap k).
// wih  -> wihP[dd][r]  (packed bf16 pairs), whh/fusB -> wgruP[dd][r].
__global__ __launch_bounds__(256) void prep_kernel(
    const float* __restrict__ w0, const float* __restrict__ w1,
    const float* __restrict__ w2, const float* __restrict__ fus_w,
    const float* __restrict__ wih, const float* __restrict__ whh,
    unsigned short* __restrict__ wB2,
    unsigned int* __restrict__ wihP, unsigned int* __restrict__ wgruP)
{
    int idx = blockIdx.x * 256 + threadIdx.x;
    if (idx < 163840) {
        int cid2  = idx >> 11;           // 0..79
        int inner = idx & 2047;
        int g = inner >> 9;
        int c = (inner >> 3) & 63;
        int e = inner & 7;
        int nh   = cid2 & 1;
        int rest = cid2 >> 1;            // 0..39
        int cq   = rest & 3;
        int m    = rest >> 2;            // 0..8 conv, 9 fusion
        int ci = cq * 32 + g * 8 + e;
        float v;
        if (m < 9) {
            int L = m / 3, k = m % 3;
            int co = nh * 64 + c;
            const float* w = (L == 0) ? w0 : ((L == 1) ? w1 : w2);
            v = w[(co * 128 + ci) * 3 + k];
        } else {
            int j = nh * 64 + c;
            v = fus_w[j * 256 + ci];     // tc half of fus_w
        }
        wB2[idx] = f2bf(v);
    } else if (idx < 163840 + 24576) {
        int f  = idx - 163840;
        int dd = f / 384;
        int r  = f % 384;
        unsigned int lo = f2bf(wih[r * 128 + 2 * dd]);
        unsigned int hi = f2bf(wih[r * 128 + 2 * dd + 1]);
        wihP[f] = (hi << 16) | lo;
    } else if (idx < 163840 + 24576 + 32768) {
        int f  = idx - 163840 - 24576;
        int dd = f >> 9;
        int r  = f & 511;
        float v0, v1;
        if (r < 384) { v0 = whh[r * 128 + 2 * dd]; v1 = whh[r * 128 + 2 * dd + 1]; }
        else { const float* fw = fus_w + (r - 384) * 256 + 128;
               v0 = fw[2 * dd]; v1 = fw[2 * dd + 1]; }
        wgruP[f] = ((unsigned int)f2bf(v1) << 16) | (unsigned int)f2bf(v0);
    }
}

// ============ kernel 1: lengths, per-s max, u_type ============
__global__ __launch_bounds__(256) void len_kernel(
    const int* __restrict__ item_id, const int* __restrict__ u_type,
    int* __restrict__ lengths, int* __restrict__ maxlen,
    float* __restrict__ u_out)
{
    int s = blockIdx.x;
    int b = threadIdx.x;
    const int* row = item_id + (b * SS + s) * II;
    int cnt = 0;
    for (int i = 0; i < II; ++i) cnt += (row[i] > 0);
    lengths[b * SS + s] = cnt;
    __shared__ int red[256];
    red[b] = cnt;
    __syncthreads();
    for (int off = 128; off > 0; off >>= 1) {
        if (b < off) red[b] = max(red[b], red[b + off]);
        __syncthreads();
    }
    if (b == 0) maxlen[s] = red[0];
    if (s == 0) u_out[b] = (float)u_type[b];
}

// ============ kernel 2: masks + mean_emb ============
__global__ __launch_bounds__(128) void mean_kernel(
    const int* __restrict__ item_id, const int* __restrict__ eval_from,
    const float* __restrict__ emb,
    const int* __restrict__ lengths, const int* __restrict__ maxlen,
    float* __restrict__ mean_emb, float* __restrict__ mask_out)
{
    int bid = blockIdx.x;
    int b = bid >> 4, s = bid & 15;
    int tid = threadIdx.x;
    __shared__ int seqs[TT];
    __shared__ int msk[TT];
    int ml  = maxlen[s];
    int len = lengths[bid];
    int ef  = eval_from[b];
    if (tid < TT) {
        int v;
        if (tid == 0) v = BOS_ID;
        else { int it = item_id[bid * II + tid - 1]; v = it > 0 ? it : 0; }
        if (tid > ml) v = 0;
        int m = (v != 0) && !(tid == len && len > 0);
        seqs[tid] = v;
        msk[tid]  = m;
        mask_out[bid * TT + tid] = (m && (s >= ef)) ? 1.0f : 0.0f;
    }
    __syncthreads();
    int cnt = 0;
    for (int p = 0; p < TT; ++p) cnt += msk[p];
    float acc = 0.0f;
    int d = tid;
    for (int p = 0; p < TT; ++p) {
        if (msk[p]) acc += emb[seqs[p] * DD + d];
    }
    mean_emb[bid * DD + d] = acc / (float)max(cnt, 1);
}

// ============ kernel 3a: gi = me @ wih^T + bih ============
__global__ __launch_bounds__(384, 1) void gi_kernel(
    const float* __restrict__ me_all, const unsigned int* __restrict__ wihP,
    const float* __restrict__ bih, float* __restrict__ gi_all)
{
    __shared__ __align__(16) unsigned int wl[64 * 384];   // 96 KB
    __shared__ __align__(16) float me[DD];
    int t   = threadIdx.x;
    int blk = blockIdx.x;
    {
        const unsigned char* g = (const unsigned char*)wihP + t * 16;
        unsigned char* l = (unsigned char*)wl + t * 16;
#pragma unroll
        for (int i = 0; i < 16; ++i) gld16(g + i * 6144, l + i * 6144);
    }
    float bi = bih[t];
    asm volatile("s_waitcnt vmcnt(0)" ::: "memory");
    __syncthreads();
    for (int q = 0; q < 16; ++q) {
        int bs = blk * 16 + q;
        if (t < DD) me[t] = me_all[bs * DD + t];
        __syncthreads();
        float acc = bi;
#pragma unroll
        for (int dd = 0; dd < 64; ++dd) {
            unsigned int u = wl[dd * 384 + t];
            float f0 = __builtin_bit_cast(float, u << 16);
            float f1 = __builtin_bit_cast(float, u & 0xffff0000u);
            acc += f0 * me[2 * dd] + f1 * me[2 * dd + 1];
        }
        gi_all[bs * 384 + t] = acc;
        __syncthreads();
    }
}

// ============ kernel 3b: sequential GRU (gh, hb) ============
__global__ __launch_bounds__(512, 1) void gru_kernel(
    const unsigned int* __restrict__ wgruP, const float* __restrict__ bhh,
    const float* __restrict__ fus_b, const float* __restrict__ gi_all,
    float* __restrict__ hB)
{
    __shared__ __align__(16) unsigned int wl[64 * 512];   // 128 KB
    __shared__ float h[DD];
    __shared__ float g_z[DD], g_inn[DD], g_hn[DD];
    int t = threadIdx.x;
    int b = blockIdx.x;
    int j = t & 127;
    int grp = t >> 7;      // 0=r, 1=z, 2=n, 3=hb
    {
        const unsigned char* g = (const unsigned char*)wgruP + t * 16;
        unsigned char* l = (unsigned char*)wl + t * 16;
#pragma unroll
        for (int i = 0; i < 16; ++i) gld16(g + i * 8192, l + i * 8192);
    }
    float bias = (t < 384) ? bhh[t] : fus_b[j];
    if (t < DD) h[t] = 0.0f;
    asm volatile("s_waitcnt vmcnt(0)" ::: "memory");
    __syncthreads();
    for (int s = 0; s < SS; ++s) {
        float gi = (grp < 3) ? gi_all[(b * SS + s) * 384 + t] : 0.0f;
        float acc = bias;
#pragma unroll
        for (int dd = 0; dd < 64; ++dd) {
            unsigned int u = wl[dd * 512 + t];
            float f0 = __builtin_bit_cast(float, u << 16);
            float f1 = __builtin_bit_cast(float, u & 0xffff0000u);
            acc += f0 * h[2 * dd] + f1 * h[2 * dd + 1];
        }
        if (grp == 3) {
            hB[(s * BB + b) * DD + j] = acc;          // h BEFORE update; fus_b included
        } else if (grp == 1) { g_z[j] = gi + acc; }
        else if (grp == 2)   { g_inn[j] = gi; g_hn[j] = acc; }
        __syncthreads();
        if (grp == 0) {
            float r = 1.0f / (1.0f + expf(-(gi + acc)));
            float z = 1.0f / (1.0f + expf(-g_z[j]));
            float n = tanhf(g_inn[j] + r * g_hn[j]);
            h[j] = (1.0f - z) * n + z * h[j];
        }
        __syncthreads();
    }
}

// ============ kernel 4: MFMA TCN + fusion (v4) ============
// 2 tiles per block, 4 waves: wave = (tile t = wv>>1, co-half nh = wv&1).
// Per wave: 5 M-tiles x 4 N-tiles, chunked K (32 ci per chunk), private
// ring-2 weight staging via global_load_lds with counted vmcnt(4).
__global__ __launch_bounds__(256, 2) void tcn_kernel(
    const int* __restrict__ item_id, const float* __restrict__ emb,
    const int* __restrict__ maxlen,
    const unsigned short* __restrict__ wB2,
    const float* __restrict__ cb0, const float* __restrict__ cb1,
    const float* __restrict__ cb2,
    const float* __restrict__ hB, float* __restrict__ reps)
{
    __shared__ __align__(16) unsigned char lds_x[2][XT];      // 44384 B
    __shared__ __align__(16) unsigned char ring[4][2][4096];  // 32768 B
    __shared__ int seqs2[2][TT];

    const int tid = threadIdx.x, bid = blockIdx.x;
    const int lane = tid & 63, wv = tid >> 6;
    const int l15 = lane & 15, q4 = lane >> 4;
    const int t = wv >> 1, nh = wv & 1;
    const int tile = bid * 2 + t;
    const int b = tile >> 4, s = tile & 15;
    const int ml = maxlen[s];

    const unsigned char* wsrc = (const unsigned char*)wB2 + nh * 4096 + lane * 16;
    unsigned char* xb = lds_x[t];

    // prologue: stage chunks 0 and 1 into ring slots 0/1 (dest is wave-uniform)
    {
#pragma unroll
        for (int i = 0; i < 4; ++i) gld16(wsrc + i * 1024, &ring[wv][0][i * 1024]);
#pragma unroll
        for (int i = 0; i < 4; ++i) gld16(wsrc + 8192 + i * 1024, &ring[wv][1][i * 1024]);
    }

    if (tid < 2 * TT) {
        int tt = tid / TT, p = tid - tt * TT;
        int tl = bid * 2 + tt;
        int v;
        if (p == 0) v = BOS_ID;
        else { int it = item_id[tl * II + p - 1]; v = it > 0 ? it : 0; }
        if (p > maxlen[tl & 15]) v = 0;
        seqs2[tt][p] = v;
    }
    // zero guard rows 0..7 of both tiles (608 dwords each)
    for (int i = tid; i < 608; i += 256) {
        *(unsigned int*)(lds_x[0] + i * 4) = 0u;
        *(unsigned int*)(lds_x[1] + i * 4) = 0u;
    }
    __syncthreads();

    // gather embeddings -> x rows 8..72 (bf16 pairs, padded rows, no swizzle)
    for (int p = nh; p < TT; p += 2) {
        const float* er = emb + (long)seqs2[t][p] * DD + lane * 2;
        float f0 = er[0], f1 = er[1];
        unsigned int pk = ((unsigned int)f2bf(f1) << 16) | (unsigned int)f2bf(f0);
        *(unsigned int*)(xb + (8 + p) * XROW + lane * 4) = pk;
    }

    // preload biases + h-part of fusion (keeps main loop free of global loads)
    float bias[3][4], hb[4];
#pragma unroll
    for (int nt = 0; nt < 4; ++nt) {
        int co = nh * 64 + nt * 16 + l15;
        bias[0][nt] = cb0[co]; bias[1][nt] = cb1[co]; bias[2][nt] = cb2[co];
        hb[nt] = hB[(s * BB + b) * DD + co];
    }
    __syncthreads();

    f32x4 acc[5][4];

#pragma unroll 1
    for (int cid = 0; cid < 40; ++cid) {
        int L = 0, cq, off, kq = 0;
        if (cid < 36) { L = cid / 12; kq = cid - L * 12; int k = kq >> 2; cq = kq & 3; off = (2 - k) << L; }
        else { cq = cid - 36; off = 0; }
        if (cid == 36 || (cid < 36 && kq == 0)) {
#pragma unroll
            for (int mt = 0; mt < 5; ++mt)
#pragma unroll
                for (int nt = 0; nt < 4; ++nt)
#pragma unroll
                    for (int r = 0; r < 4; ++r) acc[mt][nt][r] = 0.0f;
        }
        // counted wait: exactly one newer chunk (4 loads) may stay in flight
        if (cid < 39) asm volatile("s_waitcnt vmcnt(4)" ::: "memory");
        else          asm volatile("s_waitcnt vmcnt(0)" ::: "memory");

        const unsigned char* sb = &ring[wv][cid & 1][0];
        short8 bfr[4], af[5];
#pragma unroll
        for (int nt = 0; nt < 4; ++nt)
            bfr[nt] = *(const short8*)(sb + q4 * 1024 + (nt * 16 + l15) * 16);
#pragma unroll
        for (int mt = 0; mt < 5; ++mt) {
            int rowA = 8 + mt * 16 + l15 - off;
            af[mt] = *(const short8*)(xb + rowA * XROW + cq * 64 + q4 * 16);
        }
        // all ds_reads landed before we overwrite this slot with chunk cid+2
        asm volatile("s_waitcnt lgkmcnt(0)" ::: "memory");
        __builtin_amdgcn_sched_barrier(0);
        if (cid <= 37) {
            const unsigned char* src = wsrc + (size_t)(cid + 2) * 8192;
#pragma unroll
            for (int i = 0; i < 4; ++i) gld16(src + i * 1024, &ring[wv][cid & 1][i * 1024]);
        }
#pragma unroll
        for (int mt = 0; mt < 5; ++mt)
#pragma unroll
            for (int nt = 0; nt < 4; ++nt)
                acc[mt][nt] = __builtin_amdgcn_mfma_f32_16x16x32_bf16(
                    af[mt], bfr[nt], acc[mt][nt], 0, 0, 0);

        if (cid < 36 && kq == 11) {   // layer epilogue: relu(acc+bias+residual), in place
            __syncthreads();
#pragma unroll
            for (int mt = 0; mt < 5; ++mt)
#pragma unroll
                for (int nt = 0; nt < 4; ++nt) {
#pragma unroll
                    for (int r = 0; r < 4; ++r) {
                        int p = mt * 16 + q4 * 4 + r;
                        if (p < TT) {
                            int addr = (8 + p) * XROW + nh * 128 + (nt * 16 + l15) * 2;
                            float v = acc[mt][nt][r] + bias[L][nt] +
                                      bf2f(*(const unsigned short*)(xb + addr));
                            *(unsigned short*)(xb + addr) = f2bf(v > 0.f ? v : 0.f);
                        }
                    }
                }
            __syncthreads();
        }
    }

    // fusion writeout: reps[p][j] = (p<=ml) ? acc + hb : 0
    long ob = (long)tile * (TT * DD);
#pragma unroll
    for (int mt = 0; mt < 5; ++mt)
#pragma unroll
        for (int nt = 0; nt < 4; ++nt) {
            int co = nh * 64 + nt * 16 + l15;
#pragma unroll
            for (int r = 0; r < 4; ++r) {
                int p = mt * 16 + q4 * 4 + r;
                if (p < TT) {
                    float v = (p <= ml) ? (acc[mt][nt][r] + hb[nt]) : 0.0f;
                    reps[ob + p * DD + co] = v;
                }
            }
        }
}

extern "C" void kernel_launch(void* const* d_in, const int* in_sizes, int n_in,
                              void* d_out, int out_size, void* d_ws, size_t ws_size,
                              hipStream_t stream) {
    const int*   item_id   = (const int*)  d_in[0];
    const int*   eval_from = (const int*)  d_in[1];
    const int*   u_type    = (const int*)  d_in[2];
    const float* emb       = (const float*)d_in[3];
    const float* conv_w0   = (const float*)d_in[4];
    const float* conv_b0   = (const float*)d_in[5];
    const float* conv_w1   = (const float*)d_in[6];
    const float* conv_b1   = (const float*)d_in[7];
    const float* conv_w2   = (const float*)d_in[8];
    const float* conv_b2   = (const float*)d_in[9];
    const float* gru_wih   = (const float*)d_in[10];
    const float* gru_whh   = (const float*)d_in[11];
    const float* gru_bih   = (const float*)d_in[12];
    const float* gru_bhh   = (const float*)d_in[13];
    const float* fus_w     = (const float*)d_in[14];
    const float* fus_b     = (const float*)d_in[15];

    char* ws = (char*)d_ws;
    int*            lengths  = (int*)           (ws + OFF_LEN);
    int*            maxlen   = (int*)           (ws + OFF_ML);
    float*          mean_emb = (float*)         (ws + OFF_ME);
    float*          hB       = (float*)         (ws + OFF_HB);
    unsigned short* wB2      = (unsigned short*)(ws + OFF_WB2);
    unsigned int*   wihP     = (unsigned int*)  (ws + OFF_WIHP);
    unsigned int*   wgruP    = (unsigned int*)  (ws + OFF_WGRU);
    float*          gi_all   = (float*)         (ws + OFF_GI);

    float* out  = (float*)d_out;
    float* reps = out;
    float* mout = out + OUT_MASK;
    float* uout = out + OUT_UTYPE;

    prep_kernel<<<864, 256, 0, stream>>>(conv_w0, conv_w1, conv_w2, fus_w,
                                         gru_wih, gru_whh, wB2, wihP, wgruP);
    len_kernel<<<SS, 256, 0, stream>>>(item_id, u_type, lengths, maxlen, uout);
    mean_kernel<<<BB * SS, 128, 0, stream>>>(item_id, eval_from, emb, lengths, maxlen,
                                             mean_emb, mout);
    gi_kernel<<<BB, 384, 0, stream>>>(mean_emb, wihP, gru_bih, gi_all);
    gru_kernel<<<BB, 512, 0, stream>>>(wgruP, gru_bhh, fus_b, gi_all, hB);
    tcn_kernel<<<BB * SS / 2, 256, 0, stream>>>(item_id, emb, maxlen, wB2,
                                                conv_b0, conv_b1, conv_b2, hB, reps);
}